// Round 13
// baseline (287.554 us; speedup 1.0000x reference)
//
#include <hip/hip_runtime.h>

typedef short short8 __attribute__((ext_vector_type(8)));
typedef short short4v __attribute__((ext_vector_type(4)));
typedef float f32x4 __attribute__((ext_vector_type(4)));
typedef unsigned short u16;
typedef u16 ushort4v __attribute__((ext_vector_type(4)));

__device__ inline u16 f2bf(float f){
  unsigned int u = __builtin_bit_cast(unsigned int, f);
  u = (u + 0x7fffu + ((u >> 16) & 1u)) >> 16;
  return (u16)u;
}

__device__ inline short8 cat8(short4v a, short4v b){
  short8 r;
  r[0]=a[0]; r[1]=a[1]; r[2]=a[2]; r[3]=a[3];
  r[4]=b[0]; r[5]=b[1]; r[6]=b[2]; r[7]=b[3];
  return r;
}

// async global->LDS, 16B per lane. lds dest = wave-uniform base + lane*16.
__device__ inline void gload_lds16(const void* g, unsigned lds_addr){
  __builtin_amdgcn_global_load_lds((__attribute__((address_space(1))) void*)(uintptr_t)g,
                                   (__attribute__((address_space(3))) void*)(uintptr_t)lds_addr,
                                   16, 0, 0);
}

// ---------------- f32 -> bf16 convert (vectorized) ----------------
__global__ void cvt_bf16(const float* __restrict__ in, u16* __restrict__ out, int n4){
  int stride = gridDim.x * blockDim.x;
  for (int i = blockIdx.x * blockDim.x + threadIdx.x; i < n4; i += stride){
    float4 v = ((const float4*)in)[i];
    ushort4v r = { f2bf(v.x), f2bf(v.y), f2bf(v.z), f2bf(v.w) };
    ((ushort4v*)out)[i] = r;
  }
}

#define BARRIER() { __builtin_amdgcn_sched_barrier(0); __builtin_amdgcn_s_barrier(); __builtin_amdgcn_sched_barrier(0); }
#define VM4() asm volatile("s_waitcnt vmcnt(4)" ::: "memory");

// ================= 256x256 8-phase GEMM (~1092 TF/round) ==================
#define MFMA4(MO, AA, BB) { __builtin_amdgcn_s_setprio(1); \
  _Pragma("unroll") for (int m = 0; m < 4; m++) \
    _Pragma("unroll") for (int n = 0; n < 4; n++) \
      acc[(MO)+m][n] = __builtin_amdgcn_mfma_f32_16x16x32_bf16(AA[(MO)+m], BB[n], acc[(MO)+m][n], 0, 0, 0); \
  __builtin_amdgcn_s_setprio(0); }

#define PHASE4(ABASE, BBASE, ST1, ST2, ST3, ST4) { \
    const u16* Ab = (ABASE); const u16* Bb = (BBASE); \
    short8 a0[8], b0[4], a1[8], b1[4]; \
    _Pragma("unroll") for (int m = 0; m < 8; m++){ int row = wm*128 + m*16 + lr; int ph = lg ^ (row & 7); a0[m] = *(const short8*)&Ab[row*64 + ph*8]; } \
    _Pragma("unroll") for (int n = 0; n < 4; n++){ int row = wn*64 + n*16 + lr; int ph = lg ^ (row & 7); b0[n] = *(const short8*)&Bb[row*64 + ph*8]; } \
    ST1 BARRIER() MFMA4(0, a0, b0) BARRIER() \
    _Pragma("unroll") for (int m = 0; m < 8; m++){ int row = wm*128 + m*16 + lr; int ph = (4+lg) ^ (row & 7); a1[m] = *(const short8*)&Ab[row*64 + ph*8]; } \
    _Pragma("unroll") for (int n = 0; n < 4; n++){ int row = wn*64 + n*16 + lr; int ph = (4+lg) ^ (row & 7); b1[n] = *(const short8*)&Bb[row*64 + ph*8]; } \
    ST2 BARRIER() MFMA4(4, a0, b0) BARRIER() \
    ST3 BARRIER() MFMA4(0, a1, b1) BARRIER() \
    ST4 VM4() BARRIER() MFMA4(4, a1, b1) BARRIER() \
  }

template<int OUT_BF16>
__global__ __launch_bounds__(512, 2) void gemm256(const u16* __restrict__ A, const u16* __restrict__ B,
                                                  void* __restrict__ Cv, int M, int NS, int K){
  __shared__ u16 lds[2][32768];
  const int tid = threadIdx.x, wave = tid >> 6, lane = tid & 63;
  const int lr = lane & 15, lg = lane >> 4;
  const int wm = wave >> 2, wn = wave & 3;
  const long bm = blockIdx.x * 256L, bn = blockIdx.y * 256L;
  const int l3 = lane >> 3, l7 = lane & 7;

  const u16* asrc = A + (bm + wave*8 + l3) * (long)K + (l7 ^ l3) * 8;
  const u16* bsrc = B + (bn + wave*8 + l3) * (long)K + (l7 ^ l3) * 8;
  const unsigned ldsbase = (unsigned)(uintptr_t)&lds[0][0];
  const unsigned wdst = wave * 1024u;

#define STG_A(BUF,S,KOFF) gload_lds16(asrc + (size_t)(S)*64*K + (KOFF), ldsbase + (BUF)*65536u + wdst + (S)*8192u);
#define STG_B(BUF,S,KOFF) gload_lds16(bsrc + (size_t)(S)*64*K + (KOFF), ldsbase + (BUF)*65536u + 32768u + wdst + (S)*8192u);

  f32x4 acc[8][4] = {};
  const int nk = K >> 6;          // must be even

  #pragma unroll
  for (int s = 0; s < 4; s++){ STG_A(0, s, 0) }
  #pragma unroll
  for (int s = 0; s < 4; s++){ STG_B(0, s, 0) }
  #pragma unroll
  for (int s = 0; s < 4; s++){ STG_A(1, s, 64) }
  VM4()
  BARRIER()

  for (int i = 0; i < (nk >> 1); i++){
    const size_t kt1 = (size_t)((2*i + 1) << 6);
    const size_t kn0 = (size_t)(((2*i + 2) & (nk - 1)) << 6);
    const size_t kn1 = (size_t)(((2*i + 3) & (nk - 1)) << 6);
    PHASE4(&lds[0][0], &lds[0][16384],
           STG_B(1,0,kt1) STG_B(1,1,kt1),
           STG_B(1,2,kt1) STG_B(1,3,kt1),
           STG_A(0,0,kn0) STG_A(0,1,kn0),
           STG_A(0,2,kn0) STG_A(0,3,kn0))
    PHASE4(&lds[1][0], &lds[1][16384],
           STG_B(0,0,kn0) STG_B(0,1,kn0),
           STG_B(0,2,kn0) STG_B(0,3,kn0),
           STG_A(1,0,kn1) STG_A(1,1,kn1),
           STG_A(1,2,kn1) STG_A(1,3,kn1))
  }
#undef STG_A
#undef STG_B

  #pragma unroll
  for (int m = 0; m < 8; m++){
    #pragma unroll
    for (int n = 0; n < 4; n++){
      #pragma unroll
      for (int r = 0; r < 4; r++){
        long row = bm + wm*128 + m*16 + lg*4 + r;
        long col = bn + wn*64 + n*16 + lr;
        float v = acc[m][n][r];
        if (OUT_BF16) ((u16*)Cv)[row * (long)NS + col] = f2bf(v);
        else          ((float*)Cv)[row * (long)NS + col] = v;
      }
    }
  }
}

// ---------------- 128x128 m97 GEMM (862 TF; NS = output row stride) -------
template<int OUT_BF16>
__global__ __launch_bounds__(256) void gemm_bt(const u16* __restrict__ A, const u16* __restrict__ B,
                                               void* __restrict__ Cv, int M, int NS, int K){
  __shared__ u16 As[128 * 64];
  __shared__ u16 Bs[128 * 64];
  const int tid  = threadIdx.x;
  const int wave = tid >> 6, lane = tid & 63;
  const int lr = lane & 15, lg = lane >> 4;
  const int wm = wave >> 1, wn = wave & 1;
  const long bm = blockIdx.x * 128L, bn = blockIdx.y * 128L;
  const unsigned asb = (unsigned)(uintptr_t)As;
  const unsigned bsb = (unsigned)(uintptr_t)Bs;

  const int  srow = wave * 32 + (lane >> 3);
  const int  scol = ((lane & 7) ^ (lane >> 3)) * 8;
  const u16* aptr = A + (bm + srow) * (long)K + scol;
  const u16* bptr = B + (bn + srow) * (long)K + scol;
  const unsigned sdst = (unsigned)(wave * 4096);

  f32x4 acc[4][4] = {};
  for (int k0 = 0; k0 < K; k0 += 64){
    #pragma unroll
    for (int c = 0; c < 4; c++){
      gload_lds16(aptr + (size_t)(8 * c) * K + k0, asb + sdst + 1024u * c);
      gload_lds16(bptr + (size_t)(8 * c) * K + k0, bsb + sdst + 1024u * c);
    }
    __syncthreads();
    #pragma unroll
    for (int kk = 0; kk < 2; kk++){
      short8 af[4], bfr[4];
      #pragma unroll
      for (int m = 0; m < 4; m++){
        int row = wm * 64 + m * 16 + lr;
        int phys = (kk * 4 + lg) ^ (row & 7);
        af[m] = *(const short8*)&As[row * 64 + phys * 8];
      }
      #pragma unroll
      for (int n = 0; n < 4; n++){
        int row = wn * 64 + n * 16 + lr;
        int phys = (kk * 4 + lg) ^ (row & 7);
        bfr[n] = *(const short8*)&Bs[row * 64 + phys * 8];
      }
      #pragma unroll
      for (int m = 0; m < 4; m++)
        #pragma unroll
        for (int n = 0; n < 4; n++)
          acc[m][n] = __builtin_amdgcn_mfma_f32_16x16x32_bf16(af[m], bfr[n], acc[m][n], 0, 0, 0);
    }
    __syncthreads();
  }
  #pragma unroll
  for (int m = 0; m < 4; m++){
    #pragma unroll
    for (int n = 0; n < 4; n++){
      #pragma unroll
      for (int r = 0; r < 4; r++){
        long row = bm + wm*64 + m*16 + lg*4 + r;
        long col = bn + wn*64 + n*16 + lr;
        float v = acc[m][n][r];
        if (OUT_BF16) ((u16*)Cv)[row * (long)NS + col] = f2bf(v);
        else          ((float*)Cv)[row * (long)NS + col] = v;
      }
    }
  }
}

// ---------------- causal flash attention ----------------
// 512 thr = 8 waves; ONE 128-row q-tile per block; KV-tile 64.
// Grid 32x16 = 512 blocks -> 2 co-resident blocks/CU (LDS 52KB, VGPR 84):
// independent blocks overlap MFMA/softmax/staging phases. Dispatch pairing
// qt = y<8 ? 15-y : y-8 gives each CU pair uniform 34 KV-tiles.
__global__ __launch_bounds__(512, 2) void attn_fwd(const u16* __restrict__ qkv, u16* __restrict__ out){
  const int T = 2048, D3 = 6144, D = 2048, HD = 128;
  const int bh = blockIdx.x;
  const int y = blockIdx.y;             // 0..15
  const int qt = (y < 8) ? (15 - y) : (y - 8);
  const int b = bh >> 4, h = bh & 15;
  const int tid = threadIdx.x, wave = tid >> 6, lane = tid & 63;
  const int lr = lane & 15, lg = lane >> 4;

  __shared__ u16 Klds[64][136];
  __shared__ u16 Vlds[64][136];
  __shared__ u16 Plds[8][16][72];

  const size_t base = (size_t)b * T * D3;
  const unsigned vtr = (unsigned)(uintptr_t)&Vlds[(lane >> 4) * 8 + ((lane >> 2) & 3)][(lane & 3) * 4];

  const int srow = tid >> 4;
  const int scol = (tid & 15) * 8;
  const u16* kgp = qkv + base + (size_t)srow * D3 + D + h * HD + scol;
  const u16* vgp = kgp + D;

  const float scale2 = 0.12751971252971732f;  // 1/sqrt(128) * log2(e)

  const int q0 = qt * 128;
  const int q0w = q0 + wave * 16;

  short8 qf[4];
  {
    const u16* qrow = qkv + base + (size_t)(q0w + lr) * D3 + h * HD;
    #pragma unroll
    for (int kk = 0; kk < 4; kk++)
      qf[kk] = *(const short8*)(qrow + kk*32 + lg*8);
  }

  f32x4 o[8] = {};
  float mrow[4], lrw[4];
  #pragma unroll
  for (int r = 0; r < 4; r++){ mrow[r] = -1e30f; lrw[r] = 0.f; }

  const int ntiles = (q0 + 128) >> 6;
  short8 kreg[2], vreg[2];
  #pragma unroll
  for (int c = 0; c < 2; c++){
    kreg[c] = *(const short8*)(kgp + (size_t)(32 * c) * D3);
    vreg[c] = *(const short8*)(vgp + (size_t)(32 * c) * D3);
  }

  for (int t = 0; t < ntiles; t++){
    const int k0 = t * 64;
    __syncthreads();
    #pragma unroll
    for (int c = 0; c < 2; c++){
      *(short8*)&Klds[srow + 32*c][scol] = kreg[c];
      *(short8*)&Vlds[srow + 32*c][scol] = vreg[c];
    }
    __syncthreads();
    if (t + 1 < ntiles){
      const u16* kn = kgp + (size_t)(k0 + 64) * D3;
      const u16* vn = vgp + (size_t)(k0 + 64) * D3;
      #pragma unroll
      for (int c = 0; c < 2; c++){
        kreg[c] = *(const short8*)(kn + (size_t)(32 * c) * D3);
        vreg[c] = *(const short8*)(vn + (size_t)(32 * c) * D3);
      }
    }

    if (k0 <= q0w + 15){
      // ---- S = Q K^T ----
      f32x4 s[4] = {};
      #pragma unroll
      for (int kh = 0; kh < 4; kh++){
        #pragma unroll
        for (int kk = 0; kk < 4; kk++){
          short8 kfrag = *(const short8*)&Klds[kh*16 + lr][kk*32 + lg*8];
          s[kh] = __builtin_amdgcn_mfma_f32_16x16x32_bf16(qf[kk], kfrag, s[kh], 0, 0, 0);
        }
      }
      const bool need_mask = (k0 + 63 > q0w);
      #pragma unroll
      for (int kh = 0; kh < 4; kh++){
        int key = k0 + kh*16 + lr;
        #pragma unroll
        for (int r = 0; r < 4; r++){
          float v = s[kh][r] * scale2;
          if (need_mask && key > q0w + lg*4 + r) v = -1e30f;
          s[kh][r] = v;
        }
      }
      // ---- online softmax (exp2 domain, always-rescale) ----
      float fs[4];
      #pragma unroll
      for (int r = 0; r < 4; r++){
        float mx = fmaxf(fmaxf(s[0][r], s[1][r]), fmaxf(s[2][r], s[3][r]));
        #pragma unroll
        for (int msk = 8; msk >= 1; msk >>= 1)
          mx = fmaxf(mx, __shfl_xor(mx, msk, 64));
        float mnew = fmaxf(mrow[r], mx);
        float f  = exp2f(mrow[r] - mnew);
        float p0 = exp2f(s[0][r] - mnew);
        float p1 = exp2f(s[1][r] - mnew);
        float p2 = exp2f(s[2][r] - mnew);
        float p3 = exp2f(s[3][r] - mnew);
        s[0][r] = p0; s[1][r] = p1; s[2][r] = p2; s[3][r] = p3;
        float rs = (p0 + p1) + (p2 + p3);
        #pragma unroll
        for (int msk = 8; msk >= 1; msk >>= 1)
          rs += __shfl_xor(rs, msk, 64);
        lrw[r] = lrw[r] * f + rs;
        mrow[r] = mnew;
        fs[r] = f;
      }
      #pragma unroll
      for (int dt = 0; dt < 8; dt++)
        #pragma unroll
        for (int r = 0; r < 4; r++)
          o[dt][r] *= fs[r];
      // ---- P -> LDS (bf16) ----
      #pragma unroll
      for (int kh = 0; kh < 4; kh++)
        #pragma unroll
        for (int r = 0; r < 4; r++)
          Plds[wave][lg*4 + r][kh*16 + lr] = f2bf(s[kh][r]);
      asm volatile("s_waitcnt lgkmcnt(0)" ::: "memory");
      __builtin_amdgcn_sched_barrier(0);
      short8 pf[2];
      #pragma unroll
      for (int kp2 = 0; kp2 < 2; kp2++)
        pf[kp2] = *(const short8*)&Plds[wave][lr][kp2*32 + lg*8];
      asm volatile("s_waitcnt lgkmcnt(0)" ::: "memory");
      __builtin_amdgcn_sched_barrier(0);

      // ---- PV with pipelined hardware-transpose V reads ----
      short4v vf[2][2][2];
      #define TR4(BUF, PTR) \
        asm volatile("ds_read_b64_tr_b16 %0, %1"             : "=v"(vf[BUF][0][0]) : "v"(PTR)); \
        asm volatile("ds_read_b64_tr_b16 %0, %1 offset:1088" : "=v"(vf[BUF][0][1]) : "v"(PTR)); \
        asm volatile("ds_read_b64_tr_b16 %0, %1 offset:8704" : "=v"(vf[BUF][1][0]) : "v"(PTR)); \
        asm volatile("ds_read_b64_tr_b16 %0, %1 offset:9792" : "=v"(vf[BUF][1][1]) : "v"(PTR));
      TR4(0, vtr)
      #pragma unroll
      for (int dt = 0; dt < 8; dt++){
        if (dt < 7){
          unsigned pn = vtr + (unsigned)((dt + 1) * 32);
          TR4((dt + 1) & 1, pn)
          asm volatile("s_waitcnt lgkmcnt(4)" ::: "memory");
        } else {
          asm volatile("s_waitcnt lgkmcnt(0)" ::: "memory");
        }
        __builtin_amdgcn_sched_barrier(0);
        short8 v0 = cat8(vf[dt & 1][0][0], vf[dt & 1][0][1]);
        short8 v1 = cat8(vf[dt & 1][1][0], vf[dt & 1][1][1]);
        o[dt] = __builtin_amdgcn_mfma_f32_16x16x32_bf16(pf[0], v0, o[dt], 0, 0, 0);
        o[dt] = __builtin_amdgcn_mfma_f32_16x16x32_bf16(pf[1], v1, o[dt], 0, 0, 0);
      }
      #undef TR4
    }
  }
  // ---- epilogue ----
  float rl[4];
  #pragma unroll
  for (int r = 0; r < 4; r++) rl[r] = 1.0f / lrw[r];
  #pragma unroll
  for (int dt = 0; dt < 8; dt++){
    #pragma unroll
    for (int r = 0; r < 4; r++){
      float v = o[dt][r] * rl[r];
      int qa = q0w + lg*4 + r;
      out[(size_t)(b * T + qa) * D + h * HD + dt*16 + lr] = f2bf(v);
    }
  }
}

extern "C" void kernel_launch(void* const* d_in, const int* in_sizes, int n_in,
                              void* d_out, int out_size, void* d_ws, size_t ws_size,
                              hipStream_t stream) {
  const float* x    = (const float*)d_in[0];   // [2,2048,2048]
  const float* wqkv = (const float*)d_in[1];   // [6144,2048]
  const float* wout = (const float*)d_in[2];   // [2048,2048]
  float* out = (float*)d_out;                  // [2,2048,2048] f32

  u16* ws    = (u16*)d_ws;
  u16* xb    = ws;                    //  8,388,608 elems
  u16* wqkvb = xb + 8388608;          // 12,582,912 elems
  u16* qkvb  = wqkvb + 12582912;      // 25,165,824 elems
  u16* attnb = xb;                    // alias: x dead after GEMM1
  u16* woutb = wqkvb;                 // alias: wqkv dead after GEMM1

  cvt_bf16<<<2048, 256, 0, stream>>>(x,    xb,    8388608 / 4);
  cvt_bf16<<<2048, 256, 0, stream>>>(wqkv, wqkvb, 12582912 / 4);

  // qkv = x @ Wqkv^T, split for exact grid quantization:
  //   cols 0..4095  : 256^2 8-phase, 16x16 = 256 blocks (1 clean round)
  //   cols 4096..6143: 128^2 m97,    32x16 = 512 blocks (2 clean rounds)
  gemm256<1><<<dim3(16, 16), 512, 0, stream>>>(xb, wqkvb, qkvb, 4096, 6144, 2048);
  gemm_bt<1><<<dim3(32, 16), 256, 0, stream>>>(xb, wqkvb + (size_t)4096 * 2048,
                                               qkvb + 4096, 4096, 6144, 2048);

  cvt_bf16<<<2048, 256, 0, stream>>>(wout, woutb, 4194304 / 4);

  // attention: [4096][2048] bf16  (512 blocks = 2 blocks/CU, paired work)
  attn_fwd<<<dim3(32, 16), 512, 0, stream>>>(qkvb, attnb);

  // y = attn @ Wout^T : [4096][2048] f32  (32x16 = 512 blocks, 2 rounds)
  gemm_bt<0><<<dim3(32, 16), 256, 0, stream>>>(attnb, woutb, out, 4096, 2048, 2048);
}

// Round 14
// 267.171 us; speedup vs baseline: 1.0763x; 1.0763x over previous
//
#include <hip/hip_runtime.h>

typedef short short8 __attribute__((ext_vector_type(8)));
typedef short short4v __attribute__((ext_vector_type(4)));
typedef float f32x4 __attribute__((ext_vector_type(4)));
typedef unsigned short u16;
typedef unsigned int u32;
typedef u16 ushort4v __attribute__((ext_vector_type(4)));
typedef u32 u32x2 __attribute__((ext_vector_type(2)));

__device__ inline u16 f2bf(float f){
  unsigned int u = __builtin_bit_cast(unsigned int, f);
  u = (u + 0x7fffu + ((u >> 16) & 1u)) >> 16;
  return (u16)u;
}

__device__ inline short8 cat8(short4v a, short4v b){
  short8 r;
  r[0]=a[0]; r[1]=a[1]; r[2]=a[2]; r[3]=a[3];
  r[4]=b[0]; r[5]=b[1]; r[6]=b[2]; r[7]=b[3];
  return r;
}

// async global->LDS, 16B per lane. lds dest = wave-uniform base + lane*16.
__device__ inline void gload_lds16(const void* g, unsigned lds_addr){
  __builtin_amdgcn_global_load_lds((__attribute__((address_space(1))) void*)(uintptr_t)g,
                                   (__attribute__((address_space(3))) void*)(uintptr_t)lds_addr,
                                   16, 0, 0);
}

// ---------------- f32 -> bf16 convert (vectorized) ----------------
__global__ void cvt_bf16(const float* __restrict__ in, u16* __restrict__ out, int n4){
  int stride = gridDim.x * blockDim.x;
  for (int i = blockIdx.x * blockDim.x + threadIdx.x; i < n4; i += stride){
    float4 v = ((const float4*)in)[i];
    ushort4v r = { f2bf(v.x), f2bf(v.y), f2bf(v.z), f2bf(v.w) };
    ((ushort4v*)out)[i] = r;
  }
}

#define BARRIER() { __builtin_amdgcn_sched_barrier(0); __builtin_amdgcn_s_barrier(); __builtin_amdgcn_sched_barrier(0); }
#define VM4() asm volatile("s_waitcnt vmcnt(4)" ::: "memory");

// ================= 256x256 8-phase GEMM (~1092 TF/round) ==================
#define MFMA4(MO, AA, BB) { __builtin_amdgcn_s_setprio(1); \
  _Pragma("unroll") for (int m = 0; m < 4; m++) \
    _Pragma("unroll") for (int n = 0; n < 4; n++) \
      acc[(MO)+m][n] = __builtin_amdgcn_mfma_f32_16x16x32_bf16(AA[(MO)+m], BB[n], acc[(MO)+m][n], 0, 0, 0); \
  __builtin_amdgcn_s_setprio(0); }

#define PHASE4(ABASE, BBASE, ST1, ST2, ST3, ST4) { \
    const u16* Ab = (ABASE); const u16* Bb = (BBASE); \
    short8 a0[8], b0[4], a1[8], b1[4]; \
    _Pragma("unroll") for (int m = 0; m < 8; m++){ int row = wm*128 + m*16 + lr; int ph = lg ^ (row & 7); a0[m] = *(const short8*)&Ab[row*64 + ph*8]; } \
    _Pragma("unroll") for (int n = 0; n < 4; n++){ int row = wn*64 + n*16 + lr; int ph = lg ^ (row & 7); b0[n] = *(const short8*)&Bb[row*64 + ph*8]; } \
    ST1 BARRIER() MFMA4(0, a0, b0) BARRIER() \
    _Pragma("unroll") for (int m = 0; m < 8; m++){ int row = wm*128 + m*16 + lr; int ph = (4+lg) ^ (row & 7); a1[m] = *(const short8*)&Ab[row*64 + ph*8]; } \
    _Pragma("unroll") for (int n = 0; n < 4; n++){ int row = wn*64 + n*16 + lr; int ph = (4+lg) ^ (row & 7); b1[n] = *(const short8*)&Bb[row*64 + ph*8]; } \
    ST2 BARRIER() MFMA4(4, a0, b0) BARRIER() \
    ST3 BARRIER() MFMA4(0, a1, b1) BARRIER() \
    ST4 VM4() BARRIER() MFMA4(4, a1, b1) BARRIER() \
  }

template<int OUT_BF16>
__global__ __launch_bounds__(512, 2) void gemm256(const u16* __restrict__ A, const u16* __restrict__ B,
                                                  void* __restrict__ Cv, int M, int NS, int K){
  __shared__ u16 lds[2][32768];
  const int tid = threadIdx.x, wave = tid >> 6, lane = tid & 63;
  const int lr = lane & 15, lg = lane >> 4;
  const int wm = wave >> 2, wn = wave & 3;
  const long bm = blockIdx.x * 256L, bn = blockIdx.y * 256L;
  const int l3 = lane >> 3, l7 = lane & 7;

  const u16* asrc = A + (bm + wave*8 + l3) * (long)K + (l7 ^ l3) * 8;
  const u16* bsrc = B + (bn + wave*8 + l3) * (long)K + (l7 ^ l3) * 8;
  const unsigned ldsbase = (unsigned)(uintptr_t)&lds[0][0];
  const unsigned wdst = wave * 1024u;

#define STG_A(BUF,S,KOFF) gload_lds16(asrc + (size_t)(S)*64*K + (KOFF), ldsbase + (BUF)*65536u + wdst + (S)*8192u);
#define STG_B(BUF,S,KOFF) gload_lds16(bsrc + (size_t)(S)*64*K + (KOFF), ldsbase + (BUF)*65536u + 32768u + wdst + (S)*8192u);

  f32x4 acc[8][4] = {};
  const int nk = K >> 6;          // must be even

  #pragma unroll
  for (int s = 0; s < 4; s++){ STG_A(0, s, 0) }
  #pragma unroll
  for (int s = 0; s < 4; s++){ STG_B(0, s, 0) }
  #pragma unroll
  for (int s = 0; s < 4; s++){ STG_A(1, s, 64) }
  VM4()
  BARRIER()

  for (int i = 0; i < (nk >> 1); i++){
    const size_t kt1 = (size_t)((2*i + 1) << 6);
    const size_t kn0 = (size_t)(((2*i + 2) & (nk - 1)) << 6);
    const size_t kn1 = (size_t)(((2*i + 3) & (nk - 1)) << 6);
    PHASE4(&lds[0][0], &lds[0][16384],
           STG_B(1,0,kt1) STG_B(1,1,kt1),
           STG_B(1,2,kt1) STG_B(1,3,kt1),
           STG_A(0,0,kn0) STG_A(0,1,kn0),
           STG_A(0,2,kn0) STG_A(0,3,kn0))
    PHASE4(&lds[1][0], &lds[1][16384],
           STG_B(0,0,kn0) STG_B(0,1,kn0),
           STG_B(0,2,kn0) STG_B(0,3,kn0),
           STG_A(1,0,kn1) STG_A(1,1,kn1),
           STG_A(1,2,kn1) STG_A(1,3,kn1))
  }
#undef STG_A
#undef STG_B

  #pragma unroll
  for (int m = 0; m < 8; m++){
    #pragma unroll
    for (int n = 0; n < 4; n++){
      #pragma unroll
      for (int r = 0; r < 4; r++){
        long row = bm + wm*128 + m*16 + lg*4 + r;
        long col = bn + wn*64 + n*16 + lr;
        float v = acc[m][n][r];
        if (OUT_BF16) ((u16*)Cv)[row * (long)NS + col] = f2bf(v);
        else          ((float*)Cv)[row * (long)NS + col] = v;
      }
    }
  }
}

// ---------------- 128x128 m97 GEMM (862 TF; NS = output row stride) -------
template<int OUT_BF16>
__global__ __launch_bounds__(256) void gemm_bt(const u16* __restrict__ A, const u16* __restrict__ B,
                                               void* __restrict__ Cv, int M, int NS, int K){
  __shared__ u16 As[128 * 64];
  __shared__ u16 Bs[128 * 64];
  const int tid  = threadIdx.x;
  const int wave = tid >> 6, lane = tid & 63;
  const int lr = lane & 15, lg = lane >> 4;
  const int wm = wave >> 1, wn = wave & 1;
  const long bm = blockIdx.x * 128L, bn = blockIdx.y * 128L;
  const unsigned asb = (unsigned)(uintptr_t)As;
  const unsigned bsb = (unsigned)(uintptr_t)Bs;

  const int  srow = wave * 32 + (lane >> 3);
  const int  scol = ((lane & 7) ^ (lane >> 3)) * 8;
  const u16* aptr = A + (bm + srow) * (long)K + scol;
  const u16* bptr = B + (bn + srow) * (long)K + scol;
  const unsigned sdst = (unsigned)(wave * 4096);

  f32x4 acc[4][4] = {};
  for (int k0 = 0; k0 < K; k0 += 64){
    #pragma unroll
    for (int c = 0; c < 4; c++){
      gload_lds16(aptr + (size_t)(8 * c) * K + k0, asb + sdst + 1024u * c);
      gload_lds16(bptr + (size_t)(8 * c) * K + k0, bsb + sdst + 1024u * c);
    }
    __syncthreads();
    #pragma unroll
    for (int kk = 0; kk < 2; kk++){
      short8 af[4], bfr[4];
      #pragma unroll
      for (int m = 0; m < 4; m++){
        int row = wm * 64 + m * 16 + lr;
        int phys = (kk * 4 + lg) ^ (row & 7);
        af[m] = *(const short8*)&As[row * 64 + phys * 8];
      }
      #pragma unroll
      for (int n = 0; n < 4; n++){
        int row = wn * 64 + n * 16 + lr;
        int phys = (kk * 4 + lg) ^ (row & 7);
        bfr[n] = *(const short8*)&Bs[row * 64 + phys * 8];
      }
      #pragma unroll
      for (int m = 0; m < 4; m++)
        #pragma unroll
        for (int n = 0; n < 4; n++)
          acc[m][n] = __builtin_amdgcn_mfma_f32_16x16x32_bf16(af[m], bfr[n], acc[m][n], 0, 0, 0);
    }
    __syncthreads();
  }
  #pragma unroll
  for (int m = 0; m < 4; m++){
    #pragma unroll
    for (int n = 0; n < 4; n++){
      #pragma unroll
      for (int r = 0; r < 4; r++){
        long row = bm + wm*64 + m*16 + lg*4 + r;
        long col = bn + wn*64 + n*16 + lr;
        float v = acc[m][n][r];
        if (OUT_BF16) ((u16*)Cv)[row * (long)NS + col] = f2bf(v);
        else          ((float*)Cv)[row * (long)NS + col] = v;
      }
    }
  }
}

// ---------------- causal flash attention ----------------
// r12 grid (32x8, two q-tiles per block), upgraded inner loop:
//  - double-buffered K/V with ONE raw s_barrier per tile (writes to a
//    buffer are barrier-separated from its readers; t+1 global loads stay
//    in flight across the barrier)
//  - P^T per-wave LDS (PT[key][q], pitch 16): 4 ds_write_b64 per tile,
//    PV A-frags via ds_read_b64_tr_b16 (same mapping as the V path).
__global__ __launch_bounds__(512, 2) void attn_fwd(const u16* __restrict__ qkv, u16* __restrict__ out){
  const int T = 2048, D3 = 6144, D = 2048, HD = 128;
  const int bh = blockIdx.x;
  const int pr = blockIdx.y;            // 0..7
  const int b = bh >> 4, h = bh & 15;
  const int tid = threadIdx.x, wave = tid >> 6, lane = tid & 63;
  const int lr = lane & 15, lg = lane >> 4;

  __shared__ u16 Klds[2][64][136];
  __shared__ u16 Vlds[2][64][136];
  __shared__ u16 PT[8][64][16];     // per-wave P^T [key][q]

  const size_t base = (size_t)b * T * D3;
  const int vrow = (lane >> 4) * 8 + ((lane >> 2) & 3);
  const int vcol = (lane & 3) * 4;
  const unsigned vtrA = (unsigned)(uintptr_t)&Vlds[0][vrow][vcol];
  const unsigned vtrB = (unsigned)(uintptr_t)&Vlds[1][vrow][vcol];
  const unsigned ptrP = (unsigned)(uintptr_t)&PT[wave][vrow][vcol];

  const int srow = tid >> 4;
  const int scol = (tid & 15) * 8;
  const u16* kgp = qkv + base + (size_t)srow * D3 + D + h * HD + scol;
  const u16* vgp = kgp + D;

  const float scale2 = 0.12751971252971732f;  // 1/sqrt(128) * log2(e)

  for (int half = 0; half < 2; half++){
    const int qt = half ? pr : (15 - pr);
    const int q0 = qt * 128;
    const int q0w = q0 + wave * 16;

    short8 qf[4];
    {
      const u16* qrow = qkv + base + (size_t)(q0w + lr) * D3 + h * HD;
      #pragma unroll
      for (int kk = 0; kk < 4; kk++)
        qf[kk] = *(const short8*)(qrow + kk*32 + lg*8);
    }

    f32x4 o[8] = {};
    float mrow[4], lrw[4];
    #pragma unroll
    for (int r = 0; r < 4; r++){ mrow[r] = -1e30f; lrw[r] = 0.f; }

    const int ntiles = (q0 + 128) >> 6;
    short8 kreg[2], vreg[2];
    #pragma unroll
    for (int c = 0; c < 2; c++){
      kreg[c] = *(const short8*)(kgp + (size_t)(32 * c) * D3);
      vreg[c] = *(const short8*)(vgp + (size_t)(32 * c) * D3);
    }

    for (int t = 0; t < ntiles; t++){
      const int k0 = t * 64;
      const int bb = t & 1;
      // ---- write staged regs -> buf bb (compiler waits the loads) ----
      #pragma unroll
      for (int c = 0; c < 2; c++){
        *(short8*)&Klds[bb][srow + 32*c][scol] = kreg[c];
        *(short8*)&Vlds[bb][srow + 32*c][scol] = vreg[c];
      }
      if (t + 1 < ntiles){                   // issue next-tile loads early
        const u16* kn = kgp + (size_t)(k0 + 64) * D3;
        const u16* vn = vgp + (size_t)(k0 + 64) * D3;
        #pragma unroll
        for (int c = 0; c < 2; c++){
          kreg[c] = *(const short8*)(kn + (size_t)(32 * c) * D3);
          vreg[c] = *(const short8*)(vn + (size_t)(32 * c) * D3);
        }
      }
      asm volatile("s_waitcnt lgkmcnt(0)" ::: "memory");
      __builtin_amdgcn_sched_barrier(0);
      __builtin_amdgcn_s_barrier();          // single barrier per tile (dbuf)
      __builtin_amdgcn_sched_barrier(0);

      if (k0 <= q0w + 15){
        // ---- S = Q K^T ----
        f32x4 s[4] = {};
        #pragma unroll
        for (int kh = 0; kh < 4; kh++){
          #pragma unroll
          for (int kk = 0; kk < 4; kk++){
            short8 kfrag = *(const short8*)&Klds[bb][kh*16 + lr][kk*32 + lg*8];
            s[kh] = __builtin_amdgcn_mfma_f32_16x16x32_bf16(qf[kk], kfrag, s[kh], 0, 0, 0);
          }
        }
        const bool need_mask = (k0 + 63 > q0w);
        #pragma unroll
        for (int kh = 0; kh < 4; kh++){
          int key = k0 + kh*16 + lr;
          #pragma unroll
          for (int r = 0; r < 4; r++){
            float v = s[kh][r] * scale2;
            if (need_mask && key > q0w + lg*4 + r) v = -1e30f;
            s[kh][r] = v;
          }
        }
        // ---- online softmax (exp2 domain, always-rescale) ----
        float fs[4];
        #pragma unroll
        for (int r = 0; r < 4; r++){
          float mx = fmaxf(fmaxf(s[0][r], s[1][r]), fmaxf(s[2][r], s[3][r]));
          #pragma unroll
          for (int msk = 8; msk >= 1; msk >>= 1)
            mx = fmaxf(mx, __shfl_xor(mx, msk, 64));
          float mnew = fmaxf(mrow[r], mx);
          float f  = exp2f(mrow[r] - mnew);
          float p0 = exp2f(s[0][r] - mnew);
          float p1 = exp2f(s[1][r] - mnew);
          float p2 = exp2f(s[2][r] - mnew);
          float p3 = exp2f(s[3][r] - mnew);
          s[0][r] = p0; s[1][r] = p1; s[2][r] = p2; s[3][r] = p3;
          float rs = (p0 + p1) + (p2 + p3);
          #pragma unroll
          for (int msk = 8; msk >= 1; msk >>= 1)
            rs += __shfl_xor(rs, msk, 64);
          lrw[r] = lrw[r] * f + rs;
          mrow[r] = mnew;
          fs[r] = f;
        }
        #pragma unroll
        for (int dt = 0; dt < 8; dt++)
          #pragma unroll
          for (int r = 0; r < 4; r++)
            o[dt][r] *= fs[r];
        // ---- P^T -> LDS: pack 4 q-values, one ds_write_b64 per kh ----
        #pragma unroll
        for (int kh = 0; kh < 4; kh++){
          u32 w01 = (u32)f2bf(s[kh][0]) | ((u32)f2bf(s[kh][1]) << 16);
          u32 w23 = (u32)f2bf(s[kh][2]) | ((u32)f2bf(s[kh][3]) << 16);
          u32x2 wv; wv[0] = w01; wv[1] = w23;
          *(u32x2*)&PT[wave][kh*16 + lr][lg*4] = wv;
        }
        asm volatile("s_waitcnt lgkmcnt(0)" ::: "memory");
        __builtin_amdgcn_sched_barrier(0);
        // ---- PV A-frags via tr reads of PT (same mapping as V path) ----
        short4v pt[2][2];
        asm volatile("ds_read_b64_tr_b16 %0, %1"             : "=v"(pt[0][0]) : "v"(ptrP));
        asm volatile("ds_read_b64_tr_b16 %0, %1 offset:128"  : "=v"(pt[0][1]) : "v"(ptrP));
        asm volatile("ds_read_b64_tr_b16 %0, %1 offset:1024" : "=v"(pt[1][0]) : "v"(ptrP));
        asm volatile("ds_read_b64_tr_b16 %0, %1 offset:1152" : "=v"(pt[1][1]) : "v"(ptrP));
        asm volatile("s_waitcnt lgkmcnt(0)" ::: "memory");
        __builtin_amdgcn_sched_barrier(0);
        short8 pf0 = cat8(pt[0][0], pt[0][1]);
        short8 pf1 = cat8(pt[1][0], pt[1][1]);

        // ---- PV with pipelined hardware-transpose V reads ----
        const unsigned vtr = bb ? vtrB : vtrA;
        short4v vf[2][2][2];
        #define TR4(BUF, PTR) \
          asm volatile("ds_read_b64_tr_b16 %0, %1"             : "=v"(vf[BUF][0][0]) : "v"(PTR)); \
          asm volatile("ds_read_b64_tr_b16 %0, %1 offset:1088" : "=v"(vf[BUF][0][1]) : "v"(PTR)); \
          asm volatile("ds_read_b64_tr_b16 %0, %1 offset:8704" : "=v"(vf[BUF][1][0]) : "v"(PTR)); \
          asm volatile("ds_read_b64_tr_b16 %0, %1 offset:9792" : "=v"(vf[BUF][1][1]) : "v"(PTR));
        TR4(0, vtr)
        #pragma unroll
        for (int dt = 0; dt < 8; dt++){
          if (dt < 7){
            unsigned pn = vtr + (unsigned)((dt + 1) * 32);
            TR4((dt + 1) & 1, pn)
            asm volatile("s_waitcnt lgkmcnt(4)" ::: "memory");
          } else {
            asm volatile("s_waitcnt lgkmcnt(0)" ::: "memory");
          }
          __builtin_amdgcn_sched_barrier(0);
          short8 v0 = cat8(vf[dt & 1][0][0], vf[dt & 1][0][1]);
          short8 v1 = cat8(vf[dt & 1][1][0], vf[dt & 1][1][1]);
          o[dt] = __builtin_amdgcn_mfma_f32_16x16x32_bf16(pf0, v0, o[dt], 0, 0, 0);
          o[dt] = __builtin_amdgcn_mfma_f32_16x16x32_bf16(pf1, v1, o[dt], 0, 0, 0);
        }
        #undef TR4
      }
    }
    // ---- epilogue for this half ----
    float rl[4];
    #pragma unroll
    for (int r = 0; r < 4; r++) rl[r] = 1.0f / lrw[r];
    #pragma unroll
    for (int dt = 0; dt < 8; dt++){
      #pragma unroll
      for (int r = 0; r < 4; r++){
        float v = o[dt][r] * rl[r];
        int qa = q0w + lg*4 + r;
        out[(size_t)(b * T + qa) * D + h * HD + dt*16 + lr] = f2bf(v);
      }
    }
  }
}

extern "C" void kernel_launch(void* const* d_in, const int* in_sizes, int n_in,
                              void* d_out, int out_size, void* d_ws, size_t ws_size,
                              hipStream_t stream) {
  const float* x    = (const float*)d_in[0];   // [2,2048,2048]
  const float* wqkv = (const float*)d_in[1];   // [6144,2048]
  const float* wout = (const float*)d_in[2];   // [2048,2048]
  float* out = (float*)d_out;                  // [2,2048,2048] f32

  u16* ws    = (u16*)d_ws;
  u16* xb    = ws;                    //  8,388,608 elems
  u16* wqkvb = xb + 8388608;          // 12,582,912 elems
  u16* qkvb  = wqkvb + 12582912;      // 25,165,824 elems
  u16* attnb = xb;                    // alias: x dead after GEMM1
  u16* woutb = wqkvb;                 // alias: wqkv dead after GEMM1

  cvt_bf16<<<2048, 256, 0, stream>>>(x,    xb,    8388608 / 4);
  cvt_bf16<<<2048, 256, 0, stream>>>(wqkv, wqkvb, 12582912 / 4);

  // qkv = x @ Wqkv^T, split for exact grid quantization:
  //   cols 0..4095  : 256^2 8-phase, 16x16 = 256 blocks (1 clean round)
  //   cols 4096..6143: 128^2 m97,    32x16 = 512 blocks (2 clean rounds)
  gemm256<1><<<dim3(16, 16), 512, 0, stream>>>(xb, wqkvb, qkvb, 4096, 6144, 2048);
  gemm_bt<1><<<dim3(32, 16), 256, 0, stream>>>(xb, wqkvb + (size_t)4096 * 2048,
                                               qkvb + 4096, 4096, 6144, 2048);

  cvt_bf16<<<2048, 256, 0, stream>>>(wout, woutb, 4194304 / 4);

  // attention: [4096][2048] bf16  (r12 grid: 32x8, two q-tiles per block)
  attn_fwd<<<dim3(32, 8), 512, 0, stream>>>(qkvb, attnb);

  // y = attn @ Wout^T : [4096][2048] f32  (32x16 = 512 blocks, 2 rounds)
  gemm_bt<0><<<dim3(32, 16), 256, 0, stream>>>(attnb, woutb, out, 4096, 2048, 2048);
}